// Round 5
// baseline (453.546 us; speedup 1.0000x reference)
//
#include <hip/hip_runtime.h>
#include <cstdint>
#include <type_traits>
#include <utility>

// ---------- types ----------
typedef __attribute__((ext_vector_type(8))) short short8;
typedef __attribute__((ext_vector_type(8))) __bf16 bf16x8_t;
typedef __attribute__((ext_vector_type(4))) float f32x4;

template <typename V, typename = void>
struct mfma_takes : std::false_type {};
template <typename V>
struct mfma_takes<V, std::void_t<decltype(__builtin_amdgcn_mfma_f32_16x16x32_bf16(
    std::declval<V>(), std::declval<V>(), std::declval<f32x4>(), 0, 0, 0))>>
    : std::true_type {};

using frag_t = std::conditional_t<mfma_takes<bf16x8_t>::value, bf16x8_t, short8>;
static_assert(mfma_takes<bf16x8_t>::value || mfma_takes<short8>::value,
              "no usable mfma_f32_16x16x32_bf16 signature");

__device__ __forceinline__ f32x4 mfma16(frag_t a, frag_t b, f32x4 c) {
  return __builtin_amdgcn_mfma_f32_16x16x32_bf16(a, b, c, 0, 0, 0);
}

// ---------- async global->LDS, 16B per lane (m97 path) ----------
__device__ __forceinline__ void gld_lds16(const void* g, void* l) {
  __builtin_amdgcn_global_load_lds(
      (const __attribute__((address_space(1))) void*)(uintptr_t)g,
      (__attribute__((address_space(3))) void*)(uint32_t)(uintptr_t)l, 16, 0, 0);
}

// ---------- fp32 -> (bf16 hi, bf16 lo) split, RNE both ----------
__device__ __forceinline__ uint16_t bf16_rne(float x) {
  uint32_t u = __builtin_bit_cast(uint32_t, x);
  u += 0x7FFFu + ((u >> 16) & 1u);
  return (uint16_t)(u >> 16);
}
__device__ __forceinline__ float bf16_up(uint16_t h) {
  uint32_t u = ((uint32_t)h) << 16;
  return __builtin_bit_cast(float, u);
}
__device__ __forceinline__ void split2(float x, uint16_t& h, uint16_t& l) {
  h = bf16_rne(x);
  float r = x - bf16_up(h);
  l = bf16_rne(r);
}

// XOR-swizzled LDS index for 64-elem (128B) rows: 16B chunk c of row r lives
// at physical chunk (c+r)&7. All b128 frag reads / uint4 stores used below
// become conflict-free (8 chunk-groups x 8 lanes cover all 32 banks/phase).
__device__ __forceinline__ int swz(int row, int col) {
  return row * 64 + ((((col >> 3) + row) & 7) << 3) + (col & 7);
}

// ---------- fused elementwise split pre-pass ----------
struct SplitArgs {
  const float* src[4];
  uint16_t* hi[4];
  uint16_t* lo[4];
  int n4;
};
__global__ void split_multi(SplitArgs a) {
  const int z = blockIdx.y;
  int i = blockIdx.x * 256 + threadIdx.x;
  if (i >= a.n4) return;
  float4 x = ((const float4*)a.src[z])[i];
  ushort4 h, l;
  split2(x.x, h.x, l.x);
  split2(x.y, h.y, l.y);
  split2(x.z, h.z, l.z);
  split2(x.w, h.w, l.w);
  ((ushort4*)a.hi[z])[i] = h;
  ((ushort4*)a.lo[z])[i] = l;
}

// ---------- fused QKV projection GEMM, split-bf16 x3 (unchanged) ----------
struct QKVArgs {
  const uint16_t* Ah[3];
  const uint16_t* Al[3];
  const uint16_t* Bh[3];
  const uint16_t* Bl[3];
  const float* bias[3];
  uint16_t* oH[3];
  uint16_t* oL[3];
};

__global__ __launch_bounds__(256, 3) void gemm_qkv(QKVArgs args) {
  __shared__ uint16_t lds[4][128][32];
  const int K = 1024;
  const int tid = threadIdx.x;
  const int wv = tid >> 6, lane = tid & 63;
  const int lm = lane & 15, g = lane >> 4;
  const int wm = (wv & 1) * 64, wn = (wv >> 1) * 64;
  const int z = blockIdx.z;
  const bool isT = (z == 2);
  const int t = blockIdx.x + 8 * blockIdx.y;
  const int kx = t & 7, j = t >> 3;
  const int sx = (j & 3) | ((kx & 1) << 2);
  const int sy = (j >> 2) | ((kx >> 1) << 3);
  const int gm0 = (isT ? sx : sy) * 128;
  const int gn0 = (isT ? sy : sx) * 128;

  const uint16_t* base[4] = {args.Ah[z] + (size_t)gm0 * K, args.Al[z] + (size_t)gm0 * K,
                             args.Bh[z] + (size_t)gn0 * K, args.Bl[z] + (size_t)gn0 * K};
  const int rl = lane >> 2, cl = (lane & 3) * 8;

  f32x4 acc[4][4];
#pragma unroll
  for (int a = 0; a < 4; ++a)
#pragma unroll
    for (int b = 0; b < 4; ++b) acc[a][b] = (f32x4)0.0f;

#pragma unroll 1
  for (int kt = 0; kt < K; kt += 32) {
#pragma unroll
    for (int jj = 0; jj < 8; ++jj) {
      const int c = wv + 4 * jj;
      const int p = c >> 3, r16 = (c & 7) * 16;
      gld_lds16(base[p] + (size_t)(r16 + rl) * K + kt + cl, &lds[p][r16][0]);
    }
    __syncthreads();
    frag_t af[2][4];
#pragma unroll
    for (int mf = 0; mf < 4; ++mf) {
      af[0][mf] = *(const frag_t*)&lds[0][wm + mf * 16 + lm][g * 8];
      af[1][mf] = *(const frag_t*)&lds[1][wm + mf * 16 + lm][g * 8];
    }
#pragma unroll
    for (int nf = 0; nf < 4; ++nf) {
      frag_t bhf = *(const frag_t*)&lds[2][wn + nf * 16 + lm][g * 8];
      frag_t blf = *(const frag_t*)&lds[3][wn + nf * 16 + lm][g * 8];
#pragma unroll
      for (int mf = 0; mf < 4; ++mf) {
        acc[mf][nf] = mfma16(af[0][mf], bhf, acc[mf][nf]);
        acc[mf][nf] = mfma16(af[0][mf], blf, acc[mf][nf]);
        acc[mf][nf] = mfma16(af[1][mf], bhf, acc[mf][nf]);
      }
    }
    __syncthreads();
  }
  const float* bias = args.bias[z];
  uint16_t* oH = args.oH[z];
  uint16_t* oL = args.oL[z];
#pragma unroll
  for (int mf = 0; mf < 4; ++mf) {
#pragma unroll
    for (int nf = 0; nf < 4; ++nf) {
      const int col = gn0 + wn + nf * 16 + lm;
#pragma unroll
      for (int i = 0; i < 4; ++i) {
        const int row = gm0 + wm + mf * 16 + g * 4 + i;
        float v = acc[mf][nf][i] + (isT ? bias[row] : bias[col]);
        uint16_t h, l;
        split2(v, h, l);
        size_t addr;
        if (!isT) {
          addr = ((size_t)((row >> 11) * 16 + (col >> 6)) * 2048 + (row & 2047)) * 64 +
                 (col & 63);
        } else {
          addr = ((size_t)((col >> 11) * 1024 + row)) * 2048 + (col & 2047);
        }
        oH[addr] = h;
        oL[addr] = l;
      }
    }
  }
}

// ---------- O projection (unchanged) ----------
__global__ __launch_bounds__(256, 2) void gemm_o(
    const uint16_t* __restrict__ Ah, const uint16_t* __restrict__ Al,
    const uint16_t* __restrict__ Bh, const uint16_t* __restrict__ Bl,
    const float* __restrict__ bias, float* __restrict__ out) {
  const int K = 1024, N = 1024;
  __shared__ uint16_t ldsA[2][64][32];
  __shared__ uint16_t ldsB[2][128][32];
  const int tid = threadIdx.x;
  const int wv = tid >> 6, lane = tid & 63;
  const int lm = lane & 15, g = lane >> 4;
  const int wm = (wv & 1) * 32, wn = (wv >> 1) * 64;
  const int t = blockIdx.x + 8 * blockIdx.y;
  const int kx = t & 7, j = t >> 3;
  const int sx = (j & 3) | ((kx & 1) << 2);
  const int sy = (j >> 2) | ((kx >> 1) << 4);
  const int gm0 = sy * 64, gn0 = sx * 128;
  const uint16_t* baseA[2] = {Ah + (size_t)gm0 * K, Al + (size_t)gm0 * K};
  const uint16_t* baseB[2] = {Bh + (size_t)gn0 * K, Bl + (size_t)gn0 * K};
  const int rl = lane >> 2, cl = (lane & 3) * 8;

  f32x4 acc[2][4];
#pragma unroll
  for (int a = 0; a < 2; ++a)
#pragma unroll
    for (int b = 0; b < 4; ++b) acc[a][b] = (f32x4)0.0f;

#pragma unroll 1
  for (int kt = 0; kt < K; kt += 32) {
#pragma unroll
    for (int jj = 0; jj < 6; ++jj) {
      const int c = wv + 4 * jj;
      if (c < 8) {
        const int p = c >> 2, r16 = (c & 3) * 16;
        gld_lds16(baseA[p] + (size_t)(r16 + rl) * K + kt + cl, &ldsA[p][r16][0]);
      } else {
        const int b = c - 8;
        const int p = b >> 3, r16 = (b & 7) * 16;
        gld_lds16(baseB[p] + (size_t)(r16 + rl) * K + kt + cl, &ldsB[p][r16][0]);
      }
    }
    __syncthreads();
    frag_t af[2][2];
#pragma unroll
    for (int mf = 0; mf < 2; ++mf) {
      af[0][mf] = *(const frag_t*)&ldsA[0][wm + mf * 16 + lm][g * 8];
      af[1][mf] = *(const frag_t*)&ldsA[1][wm + mf * 16 + lm][g * 8];
    }
#pragma unroll
    for (int nf = 0; nf < 4; ++nf) {
      frag_t bhf = *(const frag_t*)&ldsB[0][wn + nf * 16 + lm][g * 8];
      frag_t blf = *(const frag_t*)&ldsB[1][wn + nf * 16 + lm][g * 8];
#pragma unroll
      for (int mf = 0; mf < 2; ++mf) {
        acc[mf][nf] = mfma16(af[0][mf], bhf, acc[mf][nf]);
        acc[mf][nf] = mfma16(af[0][mf], blf, acc[mf][nf]);
        acc[mf][nf] = mfma16(af[1][mf], bhf, acc[mf][nf]);
      }
    }
    __syncthreads();
  }
#pragma unroll
  for (int mf = 0; mf < 2; ++mf)
#pragma unroll
    for (int nf = 0; nf < 4; ++nf) {
      const int col = gn0 + wn + nf * 16 + lm;
#pragma unroll
      for (int i = 0; i < 4; ++i) {
        const int row = gm0 + wm + mf * 16 + g * 4 + i;
        out[(size_t)row * N + col] = acc[mf][nf][i] + bias[col];
      }
    }
}

// ---------- fused attention v4: kv-split x2 + XOR-swizzled LDS ----------
// Each block: 128 q-rows x 1024 kv (half). No softmax-max needed -> partial
// O (fp32) and partial l are pure sums; combine kernel normalizes.
// LDS 48KB (kt 16 + vt 16 + pp 16), swizzled stride-64 -> conflict-free,
// 3 blocks/CU via launch_bounds(256,3). 1024 blocks.
__global__ __launch_bounds__(256, 3) void attn_kernel(
    const uint16_t* __restrict__ Qh, const uint16_t* __restrict__ Ql,
    const uint16_t* __restrict__ Kh, const uint16_t* __restrict__ Kl,
    const uint16_t* __restrict__ Vh, const uint16_t* __restrict__ Vl,
    float* __restrict__ opart, float* __restrict__ lpart) {
  __shared__ uint16_t kt[2][4096];  // K tile [kv 64][hd 64], swizzled
  __shared__ uint16_t vt[2][4096];  // V^T tile [d 64][kv 64], swizzled
  __shared__ uint16_t pp[8192];     // P (bf16 hi) [qrow 128][kv 64], swizzled
  const int tid = threadIdx.x;
  const int wave = tid >> 6, lane = tid & 63;
  const int lm = lane & 15, g = lane >> 4;
  // grid 1024: bits [2:0]=XCD->bh low3, [6:3]=qt, [7]=half, [9:8]=bh high2
  const int linear = blockIdx.x + 32 * blockIdx.y;
  const int bh = (linear & 7) + 8 * (linear >> 8);
  const int qt = (linear >> 3) & 15;
  const int half = (linear >> 7) & 1;
  const int kvh = half * 1024;
  const size_t base = (size_t)bh * 131072;  // per (b,h): 2048*64
  const int q0 = qt * 128 + wave * 32;

  frag_t qf[2][2][2];  // [plane][b(q-16-tile)][ks]
#pragma unroll
  for (int b = 0; b < 2; ++b) {
    const size_t rb = base + (size_t)(q0 + b * 16 + lm) * 64 + g * 8;
#pragma unroll
    for (int ks = 0; ks < 2; ++ks) {
      qf[0][b][ks] = *(const frag_t*)(Qh + rb + ks * 32);
      qf[1][b][ks] = *(const frag_t*)(Ql + rb + ks * 32);
    }
  }
  f32x4 oacc[2][4];
  f32x4 lacc[2];
#pragma unroll
  for (int mf = 0; mf < 2; ++mf) {
    lacc[mf] = (f32x4)0.0f;
#pragma unroll
    for (int nf = 0; nf < 4; ++nf) oacc[mf][nf] = (f32x4)0.0f;
  }
  short8 ones_s = (short8)(short)0x3F80;
  frag_t ones = __builtin_bit_cast(frag_t, ones_s);

  const int sr = tid >> 3;       // 0..31
  const int sc = (tid & 7) * 8;  // 0..56

  uint4 kr[4], vr[4];
  auto load_k = [&](int kv0) {
    const size_t k0 = base + (size_t)(kv0 + sr) * 64 + sc;
    kr[0] = *(const uint4*)(Kh + k0);
    kr[1] = *(const uint4*)(Kh + k0 + 32 * 64);
    kr[2] = *(const uint4*)(Kl + k0);
    kr[3] = *(const uint4*)(Kl + k0 + 32 * 64);
  };
  auto load_v = [&](int kv0) {
    const size_t v0 = base + (size_t)sr * 2048 + kv0 + sc;
    vr[0] = *(const uint4*)(Vh + v0);
    vr[1] = *(const uint4*)(Vh + v0 + 32 * 2048);
    vr[2] = *(const uint4*)(Vl + v0);
    vr[3] = *(const uint4*)(Vl + v0 + 32 * 2048);
  };
  load_k(kvh);

  const float kExpScale = 0.12500000f * 1.44269504f;  // /8, exp->exp2

#pragma unroll 1
  for (int it = 0; it < 16; ++it) {
    const int kv0 = kvh + it * 64;
    *(uint4*)&kt[0][swz(sr, sc)] = kr[0];
    *(uint4*)&kt[0][swz(sr + 32, sc)] = kr[1];
    *(uint4*)&kt[1][swz(sr, sc)] = kr[2];
    *(uint4*)&kt[1][swz(sr + 32, sc)] = kr[3];
    __syncthreads();  // barrier 1: K published; prev-iter vt reads all done
    load_v(kv0);      // V loads in flight across S^T MFMAs
    f32x4 sct[4][2];
#pragma unroll
    for (int a = 0; a < 4; ++a)
#pragma unroll
      for (int b = 0; b < 2; ++b) sct[a][b] = (f32x4)0.0f;
#pragma unroll
    for (int ks = 0; ks < 2; ++ks) {
#pragma unroll
      for (int a = 0; a < 4; ++a) {
        frag_t kfh = *(const frag_t*)&kt[0][swz(a * 16 + lm, ks * 32 + g * 8)];
        frag_t kfl = *(const frag_t*)&kt[1][swz(a * 16 + lm, ks * 32 + g * 8)];
#pragma unroll
        for (int b = 0; b < 2; ++b) {
          sct[a][b] = mfma16(kfh, qf[0][b][ks], sct[a][b]);
          sct[a][b] = mfma16(kfl, qf[0][b][ks], sct[a][b]);
          sct[a][b] = mfma16(kfh, qf[1][b][ks], sct[a][b]);
        }
      }
    }
    // exp + packed P store: lane holds q=b*16+lm, kv=a*16+g*4+i (wave-local)
#pragma unroll
    for (int a = 0; a < 4; ++a) {
#pragma unroll
      for (int b = 0; b < 2; ++b) {
        ushort4 pk;
        pk.x = bf16_rne(exp2f(kExpScale * sct[a][b][0]));
        pk.y = bf16_rne(exp2f(kExpScale * sct[a][b][1]));
        pk.z = bf16_rne(exp2f(kExpScale * sct[a][b][2]));
        pk.w = bf16_rne(exp2f(kExpScale * sct[a][b][3]));
        *(ushort4*)&pp[swz(wave * 32 + b * 16 + lm, a * 16 + g * 4)] = pk;
      }
    }
    *(uint4*)&vt[0][swz(sr, sc)] = vr[0];
    *(uint4*)&vt[0][swz(sr + 32, sc)] = vr[1];
    *(uint4*)&vt[1][swz(sr, sc)] = vr[2];
    *(uint4*)&vt[1][swz(sr + 32, sc)] = vr[3];
    __syncthreads();  // barrier 2: V published; all waves' K reads done
    if (it + 1 < 16) load_k(kv0 + 64);  // next-K loads in flight across PV
#pragma unroll
    for (int ks = 0; ks < 2; ++ks) {
      frag_t pa[2];
#pragma unroll
      for (int mf = 0; mf < 2; ++mf) {
        pa[mf] = *(const frag_t*)&pp[swz(wave * 32 + mf * 16 + lm, ks * 32 + g * 8)];
        lacc[mf] = mfma16(pa[mf], ones, lacc[mf]);
      }
#pragma unroll
      for (int nf = 0; nf < 4; ++nf) {
        frag_t vbh = *(const frag_t*)&vt[0][swz(nf * 16 + lm, ks * 32 + g * 8)];
        frag_t vbl = *(const frag_t*)&vt[1][swz(nf * 16 + lm, ks * 32 + g * 8)];
#pragma unroll
        for (int mf = 0; mf < 2; ++mf) {
          oacc[mf][nf] = mfma16(pa[mf], vbh, oacc[mf][nf]);
          oacc[mf][nf] = mfma16(pa[mf], vbl, oacc[mf][nf]);
        }
      }
    }
  }
  // epilogue: fp32 partials (no normalization)
  const int obase = (half * 32 + bh) * 2048;
#pragma unroll
  for (int mf = 0; mf < 2; ++mf) {
#pragma unroll
    for (int i = 0; i < 4; ++i) {
      const int qrow = qt * 128 + wave * 32 + mf * 16 + g * 4 + i;
      float* orow = opart + ((size_t)obase + qrow) * 64;
#pragma unroll
      for (int nf = 0; nf < 4; ++nf) orow[nf * 16 + lm] = oacc[mf][nf][i];
      if (lm == 0) lpart[obase + qrow] = lacc[mf][i];
    }
  }
}

// ---------- combine partials, normalize, split to bf16 planes ----------
__global__ void combine_kernel(const float* __restrict__ opart,
                               const float* __restrict__ lpart,
                               uint16_t* __restrict__ oh, uint16_t* __restrict__ ol) {
  const int idx = blockIdx.x * 256 + threadIdx.x;  // float4 id, 0..1048575
  const float4 a = ((const float4*)opart)[idx];
  const float4 b = ((const float4*)(opart + 4194304))[idx];
  const int row = idx >> 4;  // bh*2048 + q
  const float linv = 1.0f / (lpart[row] + lpart[65536 + row]);
  const int bh = row >> 11, qq = row & 2047;
  const int bb = bh >> 4, hh = bh & 15;
  const size_t o = ((size_t)(bb * 2048 + qq)) * 1024 + hh * 64 + (idx & 15) * 4;
  ushort4 H, L;
  float v;
  v = (a.x + b.x) * linv; split2(v, H.x, L.x);
  v = (a.y + b.y) * linv; split2(v, H.y, L.y);
  v = (a.z + b.z) * linv; split2(v, H.z, L.z);
  v = (a.w + b.w) * linv; split2(v, H.w, L.w);
  *(ushort4*)(oh + o) = H;
  *(ushort4*)(ol + o) = L;
}

extern "C" void kernel_launch(void* const* d_in, const int* in_sizes, int n_in,
                              void* d_out, int out_size, void* d_ws, size_t ws_size,
                              hipStream_t stream) {
  const float* q = (const float*)d_in[0];
  const float* k = (const float*)d_in[1];
  const float* v = (const float*)d_in[2];
  const float* Wq = (const float*)d_in[3];
  const float* bq = (const float*)d_in[4];
  const float* Wk = (const float*)d_in[5];
  const float* bk = (const float*)d_in[6];
  const float* Wv = (const float*)d_in[7];
  const float* bv = (const float*)d_in[8];
  const float* Wo = (const float*)d_in[9];
  const float* bo = (const float*)d_in[10];

  const size_t NX = 4194304;  // B*S*H
  const size_t NW = 1048576;  // H*H
  uint16_t* p = (uint16_t*)d_ws;
  uint16_t* xqh = p; p += NX; uint16_t* xql = p; p += NX;
  uint16_t* xkh = p; p += NX; uint16_t* xkl = p; p += NX;
  uint16_t* xvh = p; p += NX; uint16_t* xvl = p; p += NX;
  uint16_t* wqh = p; p += NW; uint16_t* wql = p; p += NW;
  uint16_t* wkh = p; p += NW; uint16_t* wkl = p; p += NW;
  uint16_t* wvh = p; p += NW; uint16_t* wvl = p; p += NW;
  uint16_t* woh = p; p += NW; uint16_t* wol = p; p += NW;
  uint16_t* qph = p; p += NX; uint16_t* qpl = p; p += NX;
  uint16_t* kph = p; p += NX; uint16_t* kpl = p; p += NX;
  uint16_t* vth = p; p += NX; uint16_t* vtl = p; p += NX;
  uint16_t* oh = xqh;  // alias: xq consumed before combine writes o
  uint16_t* ol = xql;
  // attn partials alias the xk..wv region (dead after gemm_qkv):
  // region = 4*NX + 6*NW uint16 = 46.1 MB; need 34.1 MB.
  float* opart = (float*)xkh;           // [2][32][2048][64] fp32 = 33.6 MB
  float* lpart = opart + 2 * 4194304;   // [2][65536] fp32 = 0.5 MB

  SplitArgs sx;
  sx.src[0] = q;  sx.hi[0] = xqh; sx.lo[0] = xql;
  sx.src[1] = k;  sx.hi[1] = xkh; sx.lo[1] = xkl;
  sx.src[2] = v;  sx.hi[2] = xvh; sx.lo[2] = xvl;
  sx.src[3] = nullptr; sx.hi[3] = nullptr; sx.lo[3] = nullptr;
  sx.n4 = (int)(NX / 4);
  split_multi<<<dim3((unsigned)(NX / 4 / 256), 3), 256, 0, stream>>>(sx);

  SplitArgs sw;
  sw.src[0] = Wq; sw.hi[0] = wqh; sw.lo[0] = wql;
  sw.src[1] = Wk; sw.hi[1] = wkh; sw.lo[1] = wkl;
  sw.src[2] = Wv; sw.hi[2] = wvh; sw.lo[2] = wvl;
  sw.src[3] = Wo; sw.hi[3] = woh; sw.lo[3] = wol;
  sw.n4 = (int)(NW / 4);
  split_multi<<<dim3((unsigned)(NW / 4 / 256), 4), 256, 0, stream>>>(sw);

  QKVArgs qa;
  qa.Ah[0] = xqh; qa.Al[0] = xql; qa.Bh[0] = wqh; qa.Bl[0] = wql;
  qa.bias[0] = bq; qa.oH[0] = qph; qa.oL[0] = qpl;
  qa.Ah[1] = xkh; qa.Al[1] = xkl; qa.Bh[1] = wkh; qa.Bl[1] = wkl;
  qa.bias[1] = bk; qa.oH[1] = kph; qa.oL[1] = kpl;
  qa.Ah[2] = wvh; qa.Al[2] = wvl; qa.Bh[2] = xvh; qa.Bl[2] = xvl;  // swapped -> V^T
  qa.bias[2] = bv; qa.oH[2] = vth; qa.oL[2] = vtl;
  gemm_qkv<<<dim3(8, 32, 3), 256, 0, stream>>>(qa);

  attn_kernel<<<dim3(32, 32), 256, 0, stream>>>(qph, qpl, kph, kpl, vth, vtl,
                                                opart, lpart);
  combine_kernel<<<4096, 256, 0, stream>>>(opart, lpart, oh, ol);

  gemm_o<<<dim3(8, 64), 256, 0, stream>>>(oh, ol, woh, wol, bo, (float*)d_out);
}

// Round 6
// 448.953 us; speedup vs baseline: 1.0102x; 1.0102x over previous
//
#include <hip/hip_runtime.h>
#include <cstdint>
#include <type_traits>
#include <utility>

// ---------- types ----------
typedef __attribute__((ext_vector_type(8))) short short8;
typedef __attribute__((ext_vector_type(8))) __bf16 bf16x8_t;
typedef __attribute__((ext_vector_type(4))) float f32x4;

template <typename V, typename = void>
struct mfma_takes : std::false_type {};
template <typename V>
struct mfma_takes<V, std::void_t<decltype(__builtin_amdgcn_mfma_f32_16x16x32_bf16(
    std::declval<V>(), std::declval<V>(), std::declval<f32x4>(), 0, 0, 0))>>
    : std::true_type {};

using frag_t = std::conditional_t<mfma_takes<bf16x8_t>::value, bf16x8_t, short8>;
static_assert(mfma_takes<bf16x8_t>::value || mfma_takes<short8>::value,
              "no usable mfma_f32_16x16x32_bf16 signature");

__device__ __forceinline__ f32x4 mfma16(frag_t a, frag_t b, f32x4 c) {
  return __builtin_amdgcn_mfma_f32_16x16x32_bf16(a, b, c, 0, 0, 0);
}

// ---------- async global->LDS, 16B per lane (m97 path) ----------
__device__ __forceinline__ void gld_lds16(const void* g, void* l) {
  __builtin_amdgcn_global_load_lds(
      (const __attribute__((address_space(1))) void*)(uintptr_t)g,
      (__attribute__((address_space(3))) void*)(uint32_t)(uintptr_t)l, 16, 0, 0);
}

// ---------- fp32 -> (bf16 hi, bf16 lo) split, RNE both ----------
__device__ __forceinline__ uint16_t bf16_rne(float x) {
  uint32_t u = __builtin_bit_cast(uint32_t, x);
  u += 0x7FFFu + ((u >> 16) & 1u);
  return (uint16_t)(u >> 16);
}
__device__ __forceinline__ float bf16_up(uint16_t h) {
  uint32_t u = ((uint32_t)h) << 16;
  return __builtin_bit_cast(float, u);
}
__device__ __forceinline__ void split2(float x, uint16_t& h, uint16_t& l) {
  h = bf16_rne(x);
  float r = x - bf16_up(h);
  l = bf16_rne(r);
}

// XOR-swizzled LDS index for 64-elem (128B) rows: 16B chunk c of row r lives
// at physical chunk (c+r)&7. All b128 frag reads / uint4 stores below are
// conflict-free (verified round 5: SQ_LDS_BANK_CONFLICT 2.1e7 -> 2.1e6).
__device__ __forceinline__ int swz(int row, int col) {
  return row * 64 + ((((col >> 3) + row) & 7) << 3) + (col & 7);
}

// ---------- fused elementwise split pre-pass ----------
struct SplitArgs {
  const float* src[4];
  uint16_t* hi[4];
  uint16_t* lo[4];
  int n4;
};
__global__ void split_multi(SplitArgs a) {
  const int z = blockIdx.y;
  int i = blockIdx.x * 256 + threadIdx.x;
  if (i >= a.n4) return;
  float4 x = ((const float4*)a.src[z])[i];
  ushort4 h, l;
  split2(x.x, h.x, l.x);
  split2(x.y, h.y, l.y);
  split2(x.z, h.z, l.z);
  split2(x.w, h.w, l.w);
  ((ushort4*)a.hi[z])[i] = h;
  ((ushort4*)a.lo[z])[i] = l;
}

// ---------- fused QKV projection GEMM, split-bf16 x3 (unchanged) ----------
struct QKVArgs {
  const uint16_t* Ah[3];
  const uint16_t* Al[3];
  const uint16_t* Bh[3];
  const uint16_t* Bl[3];
  const float* bias[3];
  uint16_t* oH[3];
  uint16_t* oL[3];
};

__global__ __launch_bounds__(256, 3) void gemm_qkv(QKVArgs args) {
  __shared__ uint16_t lds[4][128][32];
  const int K = 1024;
  const int tid = threadIdx.x;
  const int wv = tid >> 6, lane = tid & 63;
  const int lm = lane & 15, g = lane >> 4;
  const int wm = (wv & 1) * 64, wn = (wv >> 1) * 64;
  const int z = blockIdx.z;
  const bool isT = (z == 2);
  const int t = blockIdx.x + 8 * blockIdx.y;
  const int kx = t & 7, j = t >> 3;
  const int sx = (j & 3) | ((kx & 1) << 2);
  const int sy = (j >> 2) | ((kx >> 1) << 3);
  const int gm0 = (isT ? sx : sy) * 128;
  const int gn0 = (isT ? sy : sx) * 128;

  const uint16_t* base[4] = {args.Ah[z] + (size_t)gm0 * K, args.Al[z] + (size_t)gm0 * K,
                             args.Bh[z] + (size_t)gn0 * K, args.Bl[z] + (size_t)gn0 * K};
  const int rl = lane >> 2, cl = (lane & 3) * 8;

  f32x4 acc[4][4];
#pragma unroll
  for (int a = 0; a < 4; ++a)
#pragma unroll
    for (int b = 0; b < 4; ++b) acc[a][b] = (f32x4)0.0f;

#pragma unroll 1
  for (int kt = 0; kt < K; kt += 32) {
#pragma unroll
    for (int jj = 0; jj < 8; ++jj) {
      const int c = wv + 4 * jj;
      const int p = c >> 3, r16 = (c & 7) * 16;
      gld_lds16(base[p] + (size_t)(r16 + rl) * K + kt + cl, &lds[p][r16][0]);
    }
    __syncthreads();
    frag_t af[2][4];
#pragma unroll
    for (int mf = 0; mf < 4; ++mf) {
      af[0][mf] = *(const frag_t*)&lds[0][wm + mf * 16 + lm][g * 8];
      af[1][mf] = *(const frag_t*)&lds[1][wm + mf * 16 + lm][g * 8];
    }
#pragma unroll
    for (int nf = 0; nf < 4; ++nf) {
      frag_t bhf = *(const frag_t*)&lds[2][wn + nf * 16 + lm][g * 8];
      frag_t blf = *(const frag_t*)&lds[3][wn + nf * 16 + lm][g * 8];
#pragma unroll
      for (int mf = 0; mf < 4; ++mf) {
        acc[mf][nf] = mfma16(af[0][mf], bhf, acc[mf][nf]);
        acc[mf][nf] = mfma16(af[0][mf], blf, acc[mf][nf]);
        acc[mf][nf] = mfma16(af[1][mf], bhf, acc[mf][nf]);
      }
    }
    __syncthreads();
  }
  const float* bias = args.bias[z];
  uint16_t* oH = args.oH[z];
  uint16_t* oL = args.oL[z];
#pragma unroll
  for (int mf = 0; mf < 4; ++mf) {
#pragma unroll
    for (int nf = 0; nf < 4; ++nf) {
      const int col = gn0 + wn + nf * 16 + lm;
#pragma unroll
      for (int i = 0; i < 4; ++i) {
        const int row = gm0 + wm + mf * 16 + g * 4 + i;
        float v = acc[mf][nf][i] + (isT ? bias[row] : bias[col]);
        uint16_t h, l;
        split2(v, h, l);
        size_t addr;
        if (!isT) {
          addr = ((size_t)((row >> 11) * 16 + (col >> 6)) * 2048 + (row & 2047)) * 64 +
                 (col & 63);
        } else {
          addr = ((size_t)((col >> 11) * 1024 + row)) * 2048 + (col & 2047);
        }
        oH[addr] = h;
        oL[addr] = l;
      }
    }
  }
}

// ---------- O projection (unchanged) ----------
__global__ __launch_bounds__(256, 2) void gemm_o(
    const uint16_t* __restrict__ Ah, const uint16_t* __restrict__ Al,
    const uint16_t* __restrict__ Bh, const uint16_t* __restrict__ Bl,
    const float* __restrict__ bias, float* __restrict__ out) {
  const int K = 1024, N = 1024;
  __shared__ uint16_t ldsA[2][64][32];
  __shared__ uint16_t ldsB[2][128][32];
  const int tid = threadIdx.x;
  const int wv = tid >> 6, lane = tid & 63;
  const int lm = lane & 15, g = lane >> 4;
  const int wm = (wv & 1) * 32, wn = (wv >> 1) * 64;
  const int t = blockIdx.x + 8 * blockIdx.y;
  const int kx = t & 7, j = t >> 3;
  const int sx = (j & 3) | ((kx & 1) << 2);
  const int sy = (j >> 2) | ((kx >> 1) << 4);
  const int gm0 = sy * 64, gn0 = sx * 128;
  const uint16_t* baseA[2] = {Ah + (size_t)gm0 * K, Al + (size_t)gm0 * K};
  const uint16_t* baseB[2] = {Bh + (size_t)gn0 * K, Bl + (size_t)gn0 * K};
  const int rl = lane >> 2, cl = (lane & 3) * 8;

  f32x4 acc[2][4];
#pragma unroll
  for (int a = 0; a < 2; ++a)
#pragma unroll
    for (int b = 0; b < 4; ++b) acc[a][b] = (f32x4)0.0f;

#pragma unroll 1
  for (int kt = 0; kt < K; kt += 32) {
#pragma unroll
    for (int jj = 0; jj < 6; ++jj) {
      const int c = wv + 4 * jj;
      if (c < 8) {
        const int p = c >> 2, r16 = (c & 3) * 16;
        gld_lds16(baseA[p] + (size_t)(r16 + rl) * K + kt + cl, &ldsA[p][r16][0]);
      } else {
        const int b = c - 8;
        const int p = b >> 3, r16 = (b & 7) * 16;
        gld_lds16(baseB[p] + (size_t)(r16 + rl) * K + kt + cl, &ldsB[p][r16][0]);
      }
    }
    __syncthreads();
    frag_t af[2][2];
#pragma unroll
    for (int mf = 0; mf < 2; ++mf) {
      af[0][mf] = *(const frag_t*)&ldsA[0][wm + mf * 16 + lm][g * 8];
      af[1][mf] = *(const frag_t*)&ldsA[1][wm + mf * 16 + lm][g * 8];
    }
#pragma unroll
    for (int nf = 0; nf < 4; ++nf) {
      frag_t bhf = *(const frag_t*)&ldsB[0][wn + nf * 16 + lm][g * 8];
      frag_t blf = *(const frag_t*)&ldsB[1][wn + nf * 16 + lm][g * 8];
#pragma unroll
      for (int mf = 0; mf < 2; ++mf) {
        acc[mf][nf] = mfma16(af[0][mf], bhf, acc[mf][nf]);
        acc[mf][nf] = mfma16(af[0][mf], blf, acc[mf][nf]);
        acc[mf][nf] = mfma16(af[1][mf], bhf, acc[mf][nf]);
      }
    }
    __syncthreads();
  }
#pragma unroll
  for (int mf = 0; mf < 2; ++mf)
#pragma unroll
    for (int nf = 0; nf < 4; ++nf) {
      const int col = gn0 + wn + nf * 16 + lm;
#pragma unroll
      for (int i = 0; i < 4; ++i) {
        const int row = gm0 + wm + mf * 16 + g * 4 + i;
        out[(size_t)row * N + col] = acc[mf][nf][i] + bias[col];
      }
    }
}

// ---------- fused attention v5: kv-split x2 + XOR swizzle, NO occupancy
// bound beyond 2 (rounds 3&5 proved (256,>=3) spills the kr/vr prefetch
// pipeline to scratch: r5 WRITE_SIZE 432MB at VGPR=80). ----------
__global__ __launch_bounds__(256, 2) void attn_kernel(
    const uint16_t* __restrict__ Qh, const uint16_t* __restrict__ Ql,
    const uint16_t* __restrict__ Kh, const uint16_t* __restrict__ Kl,
    const uint16_t* __restrict__ Vh, const uint16_t* __restrict__ Vl,
    float* __restrict__ opart, float* __restrict__ lpart) {
  __shared__ uint16_t kt[2][4096];  // K tile [kv 64][hd 64], swizzled
  __shared__ uint16_t vt[2][4096];  // V^T tile [d 64][kv 64], swizzled
  __shared__ uint16_t pp[8192];     // P (bf16 hi) [qrow 128][kv 64], swizzled
  const int tid = threadIdx.x;
  const int wave = tid >> 6, lane = tid & 63;
  const int lm = lane & 15, g = lane >> 4;
  // grid 1024: bits [2:0]=XCD->bh low3, [6:3]=qt, [7]=half, [9:8]=bh high2
  const int linear = blockIdx.x + 32 * blockIdx.y;
  const int bh = (linear & 7) + 8 * (linear >> 8);
  const int qt = (linear >> 3) & 15;
  const int half = (linear >> 7) & 1;
  const int kvh = half * 1024;
  const size_t base = (size_t)bh * 131072;  // per (b,h): 2048*64
  const int q0 = qt * 128 + wave * 32;

  frag_t qf[2][2][2];  // [plane][b(q-16-tile)][ks]
#pragma unroll
  for (int b = 0; b < 2; ++b) {
    const size_t rb = base + (size_t)(q0 + b * 16 + lm) * 64 + g * 8;
#pragma unroll
    for (int ks = 0; ks < 2; ++ks) {
      qf[0][b][ks] = *(const frag_t*)(Qh + rb + ks * 32);
      qf[1][b][ks] = *(const frag_t*)(Ql + rb + ks * 32);
    }
  }
  f32x4 oacc[2][4];
  f32x4 lacc[2];
#pragma unroll
  for (int mf = 0; mf < 2; ++mf) {
    lacc[mf] = (f32x4)0.0f;
#pragma unroll
    for (int nf = 0; nf < 4; ++nf) oacc[mf][nf] = (f32x4)0.0f;
  }
  short8 ones_s = (short8)(short)0x3F80;
  frag_t ones = __builtin_bit_cast(frag_t, ones_s);

  const int sr = tid >> 3;       // 0..31
  const int sc = (tid & 7) * 8;  // 0..56

  uint4 kr[4], vr[4];
  auto load_k = [&](int kv0) {
    const size_t k0 = base + (size_t)(kv0 + sr) * 64 + sc;
    kr[0] = *(const uint4*)(Kh + k0);
    kr[1] = *(const uint4*)(Kh + k0 + 32 * 64);
    kr[2] = *(const uint4*)(Kl + k0);
    kr[3] = *(const uint4*)(Kl + k0 + 32 * 64);
  };
  auto load_v = [&](int kv0) {
    const size_t v0 = base + (size_t)sr * 2048 + kv0 + sc;
    vr[0] = *(const uint4*)(Vh + v0);
    vr[1] = *(const uint4*)(Vh + v0 + 32 * 2048);
    vr[2] = *(const uint4*)(Vl + v0);
    vr[3] = *(const uint4*)(Vl + v0 + 32 * 2048);
  };
  load_k(kvh);

  const float kExpScale = 0.12500000f * 1.44269504f;  // /8, exp->exp2

#pragma unroll 1
  for (int it = 0; it < 16; ++it) {
    const int kv0 = kvh + it * 64;
    *(uint4*)&kt[0][swz(sr, sc)] = kr[0];
    *(uint4*)&kt[0][swz(sr + 32, sc)] = kr[1];
    *(uint4*)&kt[1][swz(sr, sc)] = kr[2];
    *(uint4*)&kt[1][swz(sr + 32, sc)] = kr[3];
    __syncthreads();  // barrier 1: K published; prev-iter vt reads all done
    load_v(kv0);      // V loads in flight across S^T MFMAs
    f32x4 sct[4][2];
#pragma unroll
    for (int a = 0; a < 4; ++a)
#pragma unroll
      for (int b = 0; b < 2; ++b) sct[a][b] = (f32x4)0.0f;
#pragma unroll
    for (int ks = 0; ks < 2; ++ks) {
#pragma unroll
      for (int a = 0; a < 4; ++a) {
        frag_t kfh = *(const frag_t*)&kt[0][swz(a * 16 + lm, ks * 32 + g * 8)];
        frag_t kfl = *(const frag_t*)&kt[1][swz(a * 16 + lm, ks * 32 + g * 8)];
#pragma unroll
        for (int b = 0; b < 2; ++b) {
          sct[a][b] = mfma16(kfh, qf[0][b][ks], sct[a][b]);
          sct[a][b] = mfma16(kfl, qf[0][b][ks], sct[a][b]);
          sct[a][b] = mfma16(kfh, qf[1][b][ks], sct[a][b]);
        }
      }
    }
    // exp + packed P store: lane holds q=b*16+lm, kv=a*16+g*4+i (wave-local)
#pragma unroll
    for (int a = 0; a < 4; ++a) {
#pragma unroll
      for (int b = 0; b < 2; ++b) {
        ushort4 pk;
        pk.x = bf16_rne(exp2f(kExpScale * sct[a][b][0]));
        pk.y = bf16_rne(exp2f(kExpScale * sct[a][b][1]));
        pk.z = bf16_rne(exp2f(kExpScale * sct[a][b][2]));
        pk.w = bf16_rne(exp2f(kExpScale * sct[a][b][3]));
        *(ushort4*)&pp[swz(wave * 32 + b * 16 + lm, a * 16 + g * 4)] = pk;
      }
    }
    *(uint4*)&vt[0][swz(sr, sc)] = vr[0];
    *(uint4*)&vt[0][swz(sr + 32, sc)] = vr[1];
    *(uint4*)&vt[1][swz(sr, sc)] = vr[2];
    *(uint4*)&vt[1][swz(sr + 32, sc)] = vr[3];
    __syncthreads();  // barrier 2: V published; all waves' K reads done
    if (it + 1 < 16) load_k(kv0 + 64);  // next-K loads in flight across PV
#pragma unroll
    for (int ks = 0; ks < 2; ++ks) {
      frag_t pa[2];
#pragma unroll
      for (int mf = 0; mf < 2; ++mf) {
        pa[mf] = *(const frag_t*)&pp[swz(wave * 32 + mf * 16 + lm, ks * 32 + g * 8)];
        lacc[mf] = mfma16(pa[mf], ones, lacc[mf]);
      }
#pragma unroll
      for (int nf = 0; nf < 4; ++nf) {
        frag_t vbh = *(const frag_t*)&vt[0][swz(nf * 16 + lm, ks * 32 + g * 8)];
        frag_t vbl = *(const frag_t*)&vt[1][swz(nf * 16 + lm, ks * 32 + g * 8)];
#pragma unroll
        for (int mf = 0; mf < 2; ++mf) {
          oacc[mf][nf] = mfma16(pa[mf], vbh, oacc[mf][nf]);
          oacc[mf][nf] = mfma16(pa[mf], vbl, oacc[mf][nf]);
        }
      }
    }
  }
  // epilogue: fp32 partials (no normalization)
  const int obase = (half * 32 + bh) * 2048;
#pragma unroll
  for (int mf = 0; mf < 2; ++mf) {
#pragma unroll
    for (int i = 0; i < 4; ++i) {
      const int qrow = qt * 128 + wave * 32 + mf * 16 + g * 4 + i;
      float* orow = opart + ((size_t)obase + qrow) * 64;
#pragma unroll
      for (int nf = 0; nf < 4; ++nf) orow[nf * 16 + lm] = oacc[mf][nf][i];
      if (lm == 0) lpart[obase + qrow] = lacc[mf][i];
    }
  }
}

// ---------- combine partials, normalize, split to bf16 planes ----------
__global__ void combine_kernel(const float* __restrict__ opart,
                               const float* __restrict__ lpart,
                               uint16_t* __restrict__ oh, uint16_t* __restrict__ ol) {
  const int idx = blockIdx.x * 256 + threadIdx.x;  // float4 id, 0..1048575
  const float4 a = ((const float4*)opart)[idx];
  const float4 b = ((const float4*)(opart + 4194304))[idx];
  const int row = idx >> 4;  // bh*2048 + q
  const float linv = 1.0f / (lpart[row] + lpart[65536 + row]);
  const int bh = row >> 11, qq = row & 2047;
  const int bb = bh >> 4, hh = bh & 15;
  const size_t o = ((size_t)(bb * 2048 + qq)) * 1024 + hh * 64 + (idx & 15) * 4;
  ushort4 H, L;
  float v;
  v = (a.x + b.x) * linv; split2(v, H.x, L.x);
  v = (a.y + b.y) * linv; split2(v, H.y, L.y);
  v = (a.z + b.z) * linv; split2(v, H.z, L.z);
  v = (a.w + b.w) * linv; split2(v, H.w, L.w);
  *(ushort4*)(oh + o) = H;
  *(ushort4*)(ol + o) = L;
}

extern "C" void kernel_launch(void* const* d_in, const int* in_sizes, int n_in,
                              void* d_out, int out_size, void* d_ws, size_t ws_size,
                              hipStream_t stream) {
  const float* q = (const float*)d_in[0];
  const float* k = (const float*)d_in[1];
  const float* v = (const float*)d_in[2];
  const float* Wq = (const float*)d_in[3];
  const float* bq = (const float*)d_in[4];
  const float* Wk = (const float*)d_in[5];
  const float* bk = (const float*)d_in[6];
  const float* Wv = (const float*)d_in[7];
  const float* bv = (const float*)d_in[8];
  const float* Wo = (const float*)d_in[9];
  const float* bo = (const float*)d_in[10];

  const size_t NX = 4194304;  // B*S*H
  const size_t NW = 1048576;  // H*H
  uint16_t* p = (uint16_t*)d_ws;
  uint16_t* xqh = p; p += NX; uint16_t* xql = p; p += NX;
  uint16_t* xkh = p; p += NX; uint16_t* xkl = p; p += NX;
  uint16_t* xvh = p; p += NX; uint16_t* xvl = p; p += NX;
  uint16_t* wqh = p; p += NW; uint16_t* wql = p; p += NW;
  uint16_t* wkh = p; p += NW; uint16_t* wkl = p; p += NW;
  uint16_t* wvh = p; p += NW; uint16_t* wvl = p; p += NW;
  uint16_t* woh = p; p += NW; uint16_t* wol = p; p += NW;
  uint16_t* qph = p; p += NX; uint16_t* qpl = p; p += NX;
  uint16_t* kph = p; p += NX; uint16_t* kpl = p; p += NX;
  uint16_t* vth = p; p += NX; uint16_t* vtl = p; p += NX;
  uint16_t* oh = xqh;  // alias: xq consumed before combine writes o
  uint16_t* ol = xql;
  // attn partials alias the xk..wv region (dead after gemm_qkv)
  float* opart = (float*)xkh;           // [2][32][2048][64] fp32 = 33.6 MB
  float* lpart = opart + 2 * 4194304;   // [2][65536] fp32 = 0.5 MB

  SplitArgs sx;
  sx.src[0] = q;  sx.hi[0] = xqh; sx.lo[0] = xql;
  sx.src[1] = k;  sx.hi[1] = xkh; sx.lo[1] = xkl;
  sx.src[2] = v;  sx.hi[2] = xvh; sx.lo[2] = xvl;
  sx.src[3] = nullptr; sx.hi[3] = nullptr; sx.lo[3] = nullptr;
  sx.n4 = (int)(NX / 4);
  split_multi<<<dim3((unsigned)(NX / 4 / 256), 3), 256, 0, stream>>>(sx);

  SplitArgs sw;
  sw.src[0] = Wq; sw.hi[0] = wqh; sw.lo[0] = wql;
  sw.src[1] = Wk; sw.hi[1] = wkh; sw.lo[1] = wkl;
  sw.src[2] = Wv; sw.hi[2] = wvh; sw.lo[2] = wvl;
  sw.src[3] = Wo; sw.hi[3] = woh; sw.lo[3] = wol;
  sw.n4 = (int)(NW / 4);
  split_multi<<<dim3((unsigned)(NW / 4 / 256), 4), 256, 0, stream>>>(sw);

  QKVArgs qa;
  qa.Ah[0] = xqh; qa.Al[0] = xql; qa.Bh[0] = wqh; qa.Bl[0] = wql;
  qa.bias[0] = bq; qa.oH[0] = qph; qa.oL[0] = qpl;
  qa.Ah[1] = xkh; qa.Al[1] = xkl; qa.Bh[1] = wkh; qa.Bl[1] = wkl;
  qa.bias[1] = bk; qa.oH[1] = kph; qa.oL[1] = kpl;
  qa.Ah[2] = wvh; qa.Al[2] = wvl; qa.Bh[2] = xvh; qa.Bl[2] = xvl;  // swapped -> V^T
  qa.bias[2] = bv; qa.oH[2] = vth; qa.oL[2] = vtl;
  gemm_qkv<<<dim3(8, 32, 3), 256, 0, stream>>>(qa);

  attn_kernel<<<dim3(32, 32), 256, 0, stream>>>(qph, qpl, kph, kpl, vth, vtl,
                                                opart, lpart);
  combine_kernel<<<4096, 256, 0, stream>>>(opart, lpart, oh, ol);

  gemm_o<<<dim3(8, 64), 256, 0, stream>>>(oh, ol, woh, wol, bo, (float*)d_out);
}

// Round 7
// 348.846 us; speedup vs baseline: 1.3001x; 1.2870x over previous
//
#include <hip/hip_runtime.h>
#include <cstdint>
#include <type_traits>
#include <utility>

// ---------- types ----------
typedef __attribute__((ext_vector_type(8))) short short8;
typedef __attribute__((ext_vector_type(8))) __bf16 bf16x8_t;
typedef __attribute__((ext_vector_type(4))) float f32x4;

template <typename V, typename = void>
struct mfma_takes : std::false_type {};
template <typename V>
struct mfma_takes<V, std::void_t<decltype(__builtin_amdgcn_mfma_f32_16x16x32_bf16(
    std::declval<V>(), std::declval<V>(), std::declval<f32x4>(), 0, 0, 0))>>
    : std::true_type {};

using frag_t = std::conditional_t<mfma_takes<bf16x8_t>::value, bf16x8_t, short8>;
static_assert(mfma_takes<bf16x8_t>::value || mfma_takes<short8>::value,
              "no usable mfma_f32_16x16x32_bf16 signature");

__device__ __forceinline__ f32x4 mfma16(frag_t a, frag_t b, f32x4 c) {
  return __builtin_amdgcn_mfma_f32_16x16x32_bf16(a, b, c, 0, 0, 0);
}

// ---------- async global->LDS, 16B per lane (m97 path) ----------
__device__ __forceinline__ void gld_lds16(const void* g, void* l) {
  __builtin_amdgcn_global_load_lds(
      (const __attribute__((address_space(1))) void*)(uintptr_t)g,
      (__attribute__((address_space(3))) void*)(uint32_t)(uintptr_t)l, 16, 0, 0);
}

// ---------- fp32 -> (bf16 hi, bf16 lo) split, RNE both ----------
__device__ __forceinline__ uint16_t bf16_rne(float x) {
  uint32_t u = __builtin_bit_cast(uint32_t, x);
  u += 0x7FFFu + ((u >> 16) & 1u);
  return (uint16_t)(u >> 16);
}
__device__ __forceinline__ float bf16_up(uint16_t h) {
  uint32_t u = ((uint32_t)h) << 16;
  return __builtin_bit_cast(float, u);
}
__device__ __forceinline__ void split2(float x, uint16_t& h, uint16_t& l) {
  h = bf16_rne(x);
  float r = x - bf16_up(h);
  l = bf16_rne(r);
}

// XOR-swizzled LDS index for 64-elem (128B) rows: 16B chunk c of row r lives
// at physical chunk (c+r)&7. Conflict-free (r5: SQ_LDS_BANK_CONFLICT 10x down).
__device__ __forceinline__ int swz(int row, int col) {
  return row * 64 + ((((col >> 3) + row) & 7) << 3) + (col & 7);
}

// ---------- fused elementwise split pre-pass ----------
struct SplitArgs {
  const float* src[4];
  uint16_t* hi[4];
  uint16_t* lo[4];
  int n4;
};
__global__ void split_multi(SplitArgs a) {
  const int z = blockIdx.y;
  int i = blockIdx.x * 256 + threadIdx.x;
  if (i >= a.n4) return;
  float4 x = ((const float4*)a.src[z])[i];
  ushort4 h, l;
  split2(x.x, h.x, l.x);
  split2(x.y, h.y, l.y);
  split2(x.z, h.z, l.z);
  split2(x.w, h.w, l.w);
  ((ushort4*)a.hi[z])[i] = h;
  ((ushort4*)a.lo[z])[i] = l;
}

// ---------- fused QKV projection GEMM, split-bf16 x3 (unchanged) ----------
struct QKVArgs {
  const uint16_t* Ah[3];
  const uint16_t* Al[3];
  const uint16_t* Bh[3];
  const uint16_t* Bl[3];
  const float* bias[3];
  uint16_t* oH[3];
  uint16_t* oL[3];
};

__global__ __launch_bounds__(256, 3) void gemm_qkv(QKVArgs args) {
  __shared__ uint16_t lds[4][128][32];
  const int K = 1024;
  const int tid = threadIdx.x;
  const int wv = tid >> 6, lane = tid & 63;
  const int lm = lane & 15, g = lane >> 4;
  const int wm = (wv & 1) * 64, wn = (wv >> 1) * 64;
  const int z = blockIdx.z;
  const bool isT = (z == 2);
  const int t = blockIdx.x + 8 * blockIdx.y;
  const int kx = t & 7, j = t >> 3;
  const int sx = (j & 3) | ((kx & 1) << 2);
  const int sy = (j >> 2) | ((kx >> 1) << 3);
  const int gm0 = (isT ? sx : sy) * 128;
  const int gn0 = (isT ? sy : sx) * 128;

  const uint16_t* base[4] = {args.Ah[z] + (size_t)gm0 * K, args.Al[z] + (size_t)gm0 * K,
                             args.Bh[z] + (size_t)gn0 * K, args.Bl[z] + (size_t)gn0 * K};
  const int rl = lane >> 2, cl = (lane & 3) * 8;

  f32x4 acc[4][4];
#pragma unroll
  for (int a = 0; a < 4; ++a)
#pragma unroll
    for (int b = 0; b < 4; ++b) acc[a][b] = (f32x4)0.0f;

#pragma unroll 1
  for (int kt = 0; kt < K; kt += 32) {
#pragma unroll
    for (int jj = 0; jj < 8; ++jj) {
      const int c = wv + 4 * jj;
      const int p = c >> 3, r16 = (c & 7) * 16;
      gld_lds16(base[p] + (size_t)(r16 + rl) * K + kt + cl, &lds[p][r16][0]);
    }
    __syncthreads();
    frag_t af[2][4];
#pragma unroll
    for (int mf = 0; mf < 4; ++mf) {
      af[0][mf] = *(const frag_t*)&lds[0][wm + mf * 16 + lm][g * 8];
      af[1][mf] = *(const frag_t*)&lds[1][wm + mf * 16 + lm][g * 8];
    }
#pragma unroll
    for (int nf = 0; nf < 4; ++nf) {
      frag_t bhf = *(const frag_t*)&lds[2][wn + nf * 16 + lm][g * 8];
      frag_t blf = *(const frag_t*)&lds[3][wn + nf * 16 + lm][g * 8];
#pragma unroll
      for (int mf = 0; mf < 4; ++mf) {
        acc[mf][nf] = mfma16(af[0][mf], bhf, acc[mf][nf]);
        acc[mf][nf] = mfma16(af[0][mf], blf, acc[mf][nf]);
        acc[mf][nf] = mfma16(af[1][mf], bhf, acc[mf][nf]);
      }
    }
    __syncthreads();
  }
  const float* bias = args.bias[z];
  uint16_t* oH = args.oH[z];
  uint16_t* oL = args.oL[z];
#pragma unroll
  for (int mf = 0; mf < 4; ++mf) {
#pragma unroll
    for (int nf = 0; nf < 4; ++nf) {
      const int col = gn0 + wn + nf * 16 + lm;
#pragma unroll
      for (int i = 0; i < 4; ++i) {
        const int row = gm0 + wm + mf * 16 + g * 4 + i;
        float v = acc[mf][nf][i] + (isT ? bias[row] : bias[col]);
        uint16_t h, l;
        split2(v, h, l);
        size_t addr;
        if (!isT) {
          addr = ((size_t)((row >> 11) * 16 + (col >> 6)) * 2048 + (row & 2047)) * 64 +
                 (col & 63);
        } else {
          addr = ((size_t)((col >> 11) * 1024 + row)) * 2048 + (col & 2047);
        }
        oH[addr] = h;
        oL[addr] = l;
      }
    }
  }
}

// ---------- O projection (unchanged) ----------
__global__ __launch_bounds__(256, 2) void gemm_o(
    const uint16_t* __restrict__ Ah, const uint16_t* __restrict__ Al,
    const uint16_t* __restrict__ Bh, const uint16_t* __restrict__ Bl,
    const float* __restrict__ bias, float* __restrict__ out) {
  const int K = 1024, N = 1024;
  __shared__ uint16_t ldsA[2][64][32];
  __shared__ uint16_t ldsB[2][128][32];
  const int tid = threadIdx.x;
  const int wv = tid >> 6, lane = tid & 63;
  const int lm = lane & 15, g = lane >> 4;
  const int wm = (wv & 1) * 32, wn = (wv >> 1) * 64;
  const int t = blockIdx.x + 8 * blockIdx.y;
  const int kx = t & 7, j = t >> 3;
  const int sx = (j & 3) | ((kx & 1) << 2);
  const int sy = (j >> 2) | ((kx >> 1) << 4);
  const int gm0 = sy * 64, gn0 = sx * 128;
  const uint16_t* baseA[2] = {Ah + (size_t)gm0 * K, Al + (size_t)gm0 * K};
  const uint16_t* baseB[2] = {Bh + (size_t)gn0 * K, Bl + (size_t)gn0 * K};
  const int rl = lane >> 2, cl = (lane & 3) * 8;

  f32x4 acc[2][4];
#pragma unroll
  for (int a = 0; a < 2; ++a)
#pragma unroll
    for (int b = 0; b < 4; ++b) acc[a][b] = (f32x4)0.0f;

#pragma unroll 1
  for (int kt = 0; kt < K; kt += 32) {
#pragma unroll
    for (int jj = 0; jj < 6; ++jj) {
      const int c = wv + 4 * jj;
      if (c < 8) {
        const int p = c >> 2, r16 = (c & 3) * 16;
        gld_lds16(baseA[p] + (size_t)(r16 + rl) * K + kt + cl, &ldsA[p][r16][0]);
      } else {
        const int b = c - 8;
        const int p = b >> 3, r16 = (b & 7) * 16;
        gld_lds16(baseB[p] + (size_t)(r16 + rl) * K + kt + cl, &ldsB[p][r16][0]);
      }
    }
    __syncthreads();
    frag_t af[2][2];
#pragma unroll
    for (int mf = 0; mf < 2; ++mf) {
      af[0][mf] = *(const frag_t*)&ldsA[0][wm + mf * 16 + lm][g * 8];
      af[1][mf] = *(const frag_t*)&ldsA[1][wm + mf * 16 + lm][g * 8];
    }
#pragma unroll
    for (int nf = 0; nf < 4; ++nf) {
      frag_t bhf = *(const frag_t*)&ldsB[0][wn + nf * 16 + lm][g * 8];
      frag_t blf = *(const frag_t*)&ldsB[1][wn + nf * 16 + lm][g * 8];
#pragma unroll
      for (int mf = 0; mf < 2; ++mf) {
        acc[mf][nf] = mfma16(af[0][mf], bhf, acc[mf][nf]);
        acc[mf][nf] = mfma16(af[0][mf], blf, acc[mf][nf]);
        acc[mf][nf] = mfma16(af[1][mf], bhf, acc[mf][nf]);
      }
    }
    __syncthreads();
  }
#pragma unroll
  for (int mf = 0; mf < 2; ++mf)
#pragma unroll
    for (int nf = 0; nf < 4; ++nf) {
      const int col = gn0 + wn + nf * 16 + lm;
#pragma unroll
      for (int i = 0; i < 4; ++i) {
        const int row = gm0 + wm + mf * 16 + g * 4 + i;
        out[(size_t)row * N + col] = acc[mf][nf][i] + bias[col];
      }
    }
}

// ---------- fused attention v6: de-lambda'd prefetch ----------
// r5/r6 evidence: kr[]/vr[] arrays captured by-ref in lambdas were NOT
// SROA-promoted -> lived in scratch (VGPR=80, WRITE_SIZE 432MB) at ANY
// launch_bounds. Fix: named uint4 scalars, inline loads. Keep swizzled LDS,
// kv-split x2, XCD map, 2-barrier pipeline, (256,2).
__global__ __launch_bounds__(256, 2) void attn_kernel(
    const uint16_t* __restrict__ Qh, const uint16_t* __restrict__ Ql,
    const uint16_t* __restrict__ Kh, const uint16_t* __restrict__ Kl,
    const uint16_t* __restrict__ Vh, const uint16_t* __restrict__ Vl,
    float* __restrict__ opart, float* __restrict__ lpart) {
  __shared__ uint16_t kt[2][4096];  // K tile [kv 64][hd 64], swizzled
  __shared__ uint16_t vt[2][4096];  // V^T tile [d 64][kv 64], swizzled
  __shared__ uint16_t pp[8192];     // P (bf16 hi) [qrow 128][kv 64], swizzled
  const int tid = threadIdx.x;
  const int wave = tid >> 6, lane = tid & 63;
  const int lm = lane & 15, g = lane >> 4;
  // grid 1024: bits [2:0]=XCD->bh low3, [6:3]=qt, [7]=half, [9:8]=bh high2
  const int linear = blockIdx.x + 32 * blockIdx.y;
  const int bh = (linear & 7) + 8 * (linear >> 8);
  const int qt = (linear >> 3) & 15;
  const int half = (linear >> 7) & 1;
  const int kvh = half * 1024;
  const size_t base = (size_t)bh * 131072;  // per (b,h): 2048*64
  const int q0 = qt * 128 + wave * 32;

  frag_t qf[2][2][2];  // [plane][b(q-16-tile)][ks]
#pragma unroll
  for (int b = 0; b < 2; ++b) {
    const size_t rb = base + (size_t)(q0 + b * 16 + lm) * 64 + g * 8;
#pragma unroll
    for (int ks = 0; ks < 2; ++ks) {
      qf[0][b][ks] = *(const frag_t*)(Qh + rb + ks * 32);
      qf[1][b][ks] = *(const frag_t*)(Ql + rb + ks * 32);
    }
  }
  f32x4 oacc[2][4];
  f32x4 lacc[2];
#pragma unroll
  for (int mf = 0; mf < 2; ++mf) {
    lacc[mf] = (f32x4)0.0f;
#pragma unroll
    for (int nf = 0; nf < 4; ++nf) oacc[mf][nf] = (f32x4)0.0f;
  }
  short8 ones_s = (short8)(short)0x3F80;
  frag_t ones = __builtin_bit_cast(frag_t, ones_s);

  const int sr = tid >> 3;       // 0..31
  const int sc = (tid & 7) * 8;  // 0..56

  // named prefetch registers (NOT arrays, NOT lambda-captured)
  uint4 kr0, kr1, kr2, kr3, vr0, vr1, vr2, vr3;
  {
    const size_t ka = base + (size_t)(kvh + sr) * 64 + sc;
    kr0 = *(const uint4*)(Kh + ka);
    kr1 = *(const uint4*)(Kh + ka + 2048);  // +32 rows
    kr2 = *(const uint4*)(Kl + ka);
    kr3 = *(const uint4*)(Kl + ka + 2048);
  }

  const float kExpScale = 0.12500000f * 1.44269504f;  // /8, exp->exp2

#pragma unroll 1
  for (int it = 0; it < 16; ++it) {
    const int kv0 = kvh + it * 64;
    *(uint4*)&kt[0][swz(sr, sc)] = kr0;
    *(uint4*)&kt[0][swz(sr + 32, sc)] = kr1;
    *(uint4*)&kt[1][swz(sr, sc)] = kr2;
    *(uint4*)&kt[1][swz(sr + 32, sc)] = kr3;
    __syncthreads();  // barrier 1: K published; prev-iter vt reads all done
    {                 // issue V loads; latency hidden by S^T MFMAs
      const size_t va = base + (size_t)sr * 2048 + kv0 + sc;
      vr0 = *(const uint4*)(Vh + va);
      vr1 = *(const uint4*)(Vh + va + 65536);  // +32 d-rows
      vr2 = *(const uint4*)(Vl + va);
      vr3 = *(const uint4*)(Vl + va + 65536);
    }
    f32x4 sct[4][2];
#pragma unroll
    for (int a = 0; a < 4; ++a)
#pragma unroll
      for (int b = 0; b < 2; ++b) sct[a][b] = (f32x4)0.0f;
#pragma unroll
    for (int ks = 0; ks < 2; ++ks) {
#pragma unroll
      for (int a = 0; a < 4; ++a) {
        frag_t kfh = *(const frag_t*)&kt[0][swz(a * 16 + lm, ks * 32 + g * 8)];
        frag_t kfl = *(const frag_t*)&kt[1][swz(a * 16 + lm, ks * 32 + g * 8)];
#pragma unroll
        for (int b = 0; b < 2; ++b) {
          sct[a][b] = mfma16(kfh, qf[0][b][ks], sct[a][b]);
          sct[a][b] = mfma16(kfl, qf[0][b][ks], sct[a][b]);
          sct[a][b] = mfma16(kfh, qf[1][b][ks], sct[a][b]);
        }
      }
    }
    // exp + packed P store: lane holds q=b*16+lm, kv=a*16+g*4+i (wave-local)
#pragma unroll
    for (int a = 0; a < 4; ++a) {
#pragma unroll
      for (int b = 0; b < 2; ++b) {
        ushort4 pk;
        pk.x = bf16_rne(exp2f(kExpScale * sct[a][b][0]));
        pk.y = bf16_rne(exp2f(kExpScale * sct[a][b][1]));
        pk.z = bf16_rne(exp2f(kExpScale * sct[a][b][2]));
        pk.w = bf16_rne(exp2f(kExpScale * sct[a][b][3]));
        *(ushort4*)&pp[swz(wave * 32 + b * 16 + lm, a * 16 + g * 4)] = pk;
      }
    }
    *(uint4*)&vt[0][swz(sr, sc)] = vr0;
    *(uint4*)&vt[0][swz(sr + 32, sc)] = vr1;
    *(uint4*)&vt[1][swz(sr, sc)] = vr2;
    *(uint4*)&vt[1][swz(sr + 32, sc)] = vr3;
    __syncthreads();  // barrier 2: V published; all waves' K reads done
    if (it + 1 < 16) {  // issue next K loads; latency hidden by PV MFMAs
      const size_t ka = base + (size_t)(kv0 + 64 + sr) * 64 + sc;
      kr0 = *(const uint4*)(Kh + ka);
      kr1 = *(const uint4*)(Kh + ka + 2048);
      kr2 = *(const uint4*)(Kl + ka);
      kr3 = *(const uint4*)(Kl + ka + 2048);
    }
#pragma unroll
    for (int ks = 0; ks < 2; ++ks) {
      frag_t pa[2];
#pragma unroll
      for (int mf = 0; mf < 2; ++mf) {
        pa[mf] = *(const frag_t*)&pp[swz(wave * 32 + mf * 16 + lm, ks * 32 + g * 8)];
        lacc[mf] = mfma16(pa[mf], ones, lacc[mf]);
      }
#pragma unroll
      for (int nf = 0; nf < 4; ++nf) {
        frag_t vbh = *(const frag_t*)&vt[0][swz(nf * 16 + lm, ks * 32 + g * 8)];
        frag_t vbl = *(const frag_t*)&vt[1][swz(nf * 16 + lm, ks * 32 + g * 8)];
#pragma unroll
        for (int mf = 0; mf < 2; ++mf) {
          oacc[mf][nf] = mfma16(pa[mf], vbh, oacc[mf][nf]);
          oacc[mf][nf] = mfma16(pa[mf], vbl, oacc[mf][nf]);
        }
      }
    }
  }
  // epilogue: fp32 partials (no normalization)
  const int obase = (half * 32 + bh) * 2048;
#pragma unroll
  for (int mf = 0; mf < 2; ++mf) {
#pragma unroll
    for (int i = 0; i < 4; ++i) {
      const int qrow = qt * 128 + wave * 32 + mf * 16 + g * 4 + i;
      float* orow = opart + ((size_t)obase + qrow) * 64;
#pragma unroll
      for (int nf = 0; nf < 4; ++nf) orow[nf * 16 + lm] = oacc[mf][nf][i];
      if (lm == 0) lpart[obase + qrow] = lacc[mf][i];
    }
  }
}

// ---------- combine partials, normalize, split to bf16 planes ----------
__global__ void combine_kernel(const float* __restrict__ opart,
                               const float* __restrict__ lpart,
                               uint16_t* __restrict__ oh, uint16_t* __restrict__ ol) {
  const int idx = blockIdx.x * 256 + threadIdx.x;  // float4 id, 0..1048575
  const float4 a = ((const float4*)opart)[idx];
  const float4 b = ((const float4*)(opart + 4194304))[idx];
  const int row = idx >> 4;  // bh*2048 + q
  const float linv = 1.0f / (lpart[row] + lpart[65536 + row]);
  const int bh = row >> 11, qq = row & 2047;
  const int bb = bh >> 4, hh = bh & 15;
  const size_t o = ((size_t)(bb * 2048 + qq)) * 1024 + hh * 64 + (idx & 15) * 4;
  ushort4 H, L;
  float v;
  v = (a.x + b.x) * linv; split2(v, H.x, L.x);
  v = (a.y + b.y) * linv; split2(v, H.y, L.y);
  v = (a.z + b.z) * linv; split2(v, H.z, L.z);
  v = (a.w + b.w) * linv; split2(v, H.w, L.w);
  *(ushort4*)(oh + o) = H;
  *(ushort4*)(ol + o) = L;
}

extern "C" void kernel_launch(void* const* d_in, const int* in_sizes, int n_in,
                              void* d_out, int out_size, void* d_ws, size_t ws_size,
                              hipStream_t stream) {
  const float* q = (const float*)d_in[0];
  const float* k = (const float*)d_in[1];
  const float* v = (const float*)d_in[2];
  const float* Wq = (const float*)d_in[3];
  const float* bq = (const float*)d_in[4];
  const float* Wk = (const float*)d_in[5];
  const float* bk = (const float*)d_in[6];
  const float* Wv = (const float*)d_in[7];
  const float* bv = (const float*)d_in[8];
  const float* Wo = (const float*)d_in[9];
  const float* bo = (const float*)d_in[10];

  const size_t NX = 4194304;  // B*S*H
  const size_t NW = 1048576;  // H*H
  uint16_t* p = (uint16_t*)d_ws;
  uint16_t* xqh = p; p += NX; uint16_t* xql = p; p += NX;
  uint16_t* xkh = p; p += NX; uint16_t* xkl = p; p += NX;
  uint16_t* xvh = p; p += NX; uint16_t* xvl = p; p += NX;
  uint16_t* wqh = p; p += NW; uint16_t* wql = p; p += NW;
  uint16_t* wkh = p; p += NW; uint16_t* wkl = p; p += NW;
  uint16_t* wvh = p; p += NW; uint16_t* wvl = p; p += NW;
  uint16_t* woh = p; p += NW; uint16_t* wol = p; p += NW;
  uint16_t* qph = p; p += NX; uint16_t* qpl = p; p += NX;
  uint16_t* kph = p; p += NX; uint16_t* kpl = p; p += NX;
  uint16_t* vth = p; p += NX; uint16_t* vtl = p; p += NX;
  uint16_t* oh = xqh;  // alias: xq consumed before combine writes o
  uint16_t* ol = xql;
  // attn partials alias the xk..wv region (dead after gemm_qkv)
  float* opart = (float*)xkh;           // [2][32][2048][64] fp32 = 33.6 MB
  float* lpart = opart + 2 * 4194304;   // [2][65536] fp32 = 0.5 MB

  SplitArgs sx;
  sx.src[0] = q;  sx.hi[0] = xqh; sx.lo[0] = xql;
  sx.src[1] = k;  sx.hi[1] = xkh; sx.lo[1] = xkl;
  sx.src[2] = v;  sx.hi[2] = xvh; sx.lo[2] = xvl;
  sx.src[3] = nullptr; sx.hi[3] = nullptr; sx.lo[3] = nullptr;
  sx.n4 = (int)(NX / 4);
  split_multi<<<dim3((unsigned)(NX / 4 / 256), 3), 256, 0, stream>>>(sx);

  SplitArgs sw;
  sw.src[0] = Wq; sw.hi[0] = wqh; sw.lo[0] = wql;
  sw.src[1] = Wk; sw.hi[1] = wkh; sw.lo[1] = wkl;
  sw.src[2] = Wv; sw.hi[2] = wvh; sw.lo[2] = wvl;
  sw.src[3] = Wo; sw.hi[3] = woh; sw.lo[3] = wol;
  sw.n4 = (int)(NW / 4);
  split_multi<<<dim3((unsigned)(NW / 4 / 256), 4), 256, 0, stream>>>(sw);

  QKVArgs qa;
  qa.Ah[0] = xqh; qa.Al[0] = xql; qa.Bh[0] = wqh; qa.Bl[0] = wql;
  qa.bias[0] = bq; qa.oH[0] = qph; qa.oL[0] = qpl;
  qa.Ah[1] = xkh; qa.Al[1] = xkl; qa.Bh[1] = wkh; qa.Bl[1] = wkl;
  qa.bias[1] = bk; qa.oH[1] = kph; qa.oL[1] = kpl;
  qa.Ah[2] = wvh; qa.Al[2] = wvl; qa.Bh[2] = xvh; qa.Bl[2] = xvl;  // swapped -> V^T
  qa.bias[2] = bv; qa.oH[2] = vth; qa.oL[2] = vtl;
  gemm_qkv<<<dim3(8, 32, 3), 256, 0, stream>>>(qa);

  attn_kernel<<<dim3(32, 32), 256, 0, stream>>>(qph, qpl, kph, kpl, vth, vtl,
                                                opart, lpart);
  combine_kernel<<<4096, 256, 0, stream>>>(opart, lpart, oh, ol);

  gemm_o<<<dim3(8, 64), 256, 0, stream>>>(oh, ol, woh, wol, bo, (float*)d_out);
}

// Round 8
// 306.071 us; speedup vs baseline: 1.4818x; 1.1398x over previous
//
#include <hip/hip_runtime.h>
#include <cstdint>
#include <type_traits>
#include <utility>

// ---------- types ----------
typedef __attribute__((ext_vector_type(8))) short short8;
typedef __attribute__((ext_vector_type(8))) __bf16 bf16x8_t;
typedef __attribute__((ext_vector_type(4))) float f32x4;

template <typename V, typename = void>
struct mfma_takes : std::false_type {};
template <typename V>
struct mfma_takes<V, std::void_t<decltype(__builtin_amdgcn_mfma_f32_16x16x32_bf16(
    std::declval<V>(), std::declval<V>(), std::declval<f32x4>(), 0, 0, 0))>>
    : std::true_type {};

using frag_t = std::conditional_t<mfma_takes<bf16x8_t>::value, bf16x8_t, short8>;
static_assert(mfma_takes<bf16x8_t>::value || mfma_takes<short8>::value,
              "no usable mfma_f32_16x16x32_bf16 signature");

__device__ __forceinline__ f32x4 mfma16(frag_t a, frag_t b, f32x4 c) {
  return __builtin_amdgcn_mfma_f32_16x16x32_bf16(a, b, c, 0, 0, 0);
}

// ---------- async global->LDS, 16B per lane (m97 path) ----------
__device__ __forceinline__ void gld_lds16(const void* g, void* l) {
  __builtin_amdgcn_global_load_lds(
      (const __attribute__((address_space(1))) void*)(uintptr_t)g,
      (__attribute__((address_space(3))) void*)(uint32_t)(uintptr_t)l, 16, 0, 0);
}

// ---------- fp32 -> (bf16 hi, bf16 lo) split, RNE both ----------
__device__ __forceinline__ uint16_t bf16_rne(float x) {
  uint32_t u = __builtin_bit_cast(uint32_t, x);
  u += 0x7FFFu + ((u >> 16) & 1u);
  return (uint16_t)(u >> 16);
}
__device__ __forceinline__ float bf16_up(uint16_t h) {
  uint32_t u = ((uint32_t)h) << 16;
  return __builtin_bit_cast(float, u);
}
__device__ __forceinline__ void split2(float x, uint16_t& h, uint16_t& l) {
  h = bf16_rne(x);
  float r = x - bf16_up(h);
  l = bf16_rne(r);
}

// XOR-swizzled LDS index for 64-elem (128B) rows: conflict-free (r5-verified).
__device__ __forceinline__ int swz(int row, int col) {
  return row * 64 + ((((col >> 3) + row) & 7) << 3) + (col & 7);
}

// ---------- fused elementwise split pre-pass (lo optional) ----------
struct SplitArgs {
  const float* src[4];
  uint16_t* hi[4];
  uint16_t* lo[4];  // nullptr -> hi-only
  int n4;
};
__global__ void split_multi(SplitArgs a) {
  const int z = blockIdx.y;
  int i = blockIdx.x * 256 + threadIdx.x;
  if (i >= a.n4) return;
  float4 x = ((const float4*)a.src[z])[i];
  ushort4 h, l;
  split2(x.x, h.x, l.x);
  split2(x.y, h.y, l.y);
  split2(x.z, h.z, l.z);
  split2(x.w, h.w, l.w);
  ((ushort4*)a.hi[z])[i] = h;
  if (a.lo[z]) ((ushort4*)a.lo[z])[i] = l;
}

// ---------- fused QKV projection GEMM, split-bf16 x2 ----------
// acc = (Ah+Al)*Bh : drops A*Bl term (~2^-9 rel; within error budget).
// z=0,1: C = X(hi,lo) * Wh^T -> [B,nh,S,hd] hi+lo planes (bias[col])
// z=2:   C = Wv(hi,lo) * Xvh^T -> [B,nh,hd,S] hi-ONLY plane (bias[row])
struct QKVArgs {
  const uint16_t* Ah[3];
  const uint16_t* Al[3];
  const uint16_t* Bh[3];
  const float* bias[3];
  uint16_t* oH[3];
  uint16_t* oL[3];
};

__global__ __launch_bounds__(256, 3) void gemm_qkv(QKVArgs args) {
  __shared__ uint16_t lds[3][128][32];  // Ah, Al, Bh (24 KB)
  const int K = 1024;
  const int tid = threadIdx.x;
  const int wv = tid >> 6, lane = tid & 63;
  const int lm = lane & 15, g = lane >> 4;
  const int wm = (wv & 1) * 64, wn = (wv >> 1) * 64;
  const int z = blockIdx.z;
  const bool isT = (z == 2);
  const int t = blockIdx.x + 8 * blockIdx.y;
  const int kx = t & 7, j = t >> 3;
  const int sx = (j & 3) | ((kx & 1) << 2);
  const int sy = (j >> 2) | ((kx >> 1) << 3);
  const int gm0 = (isT ? sx : sy) * 128;
  const int gn0 = (isT ? sy : sx) * 128;

  const uint16_t* base[3] = {args.Ah[z] + (size_t)gm0 * K, args.Al[z] + (size_t)gm0 * K,
                             args.Bh[z] + (size_t)gn0 * K};
  const int rl = lane >> 2, cl = (lane & 3) * 8;

  f32x4 acc[4][4];
#pragma unroll
  for (int a = 0; a < 4; ++a)
#pragma unroll
    for (int b = 0; b < 4; ++b) acc[a][b] = (f32x4)0.0f;

#pragma unroll 1
  for (int kt = 0; kt < K; kt += 32) {
    // 24 chunks of 1KB; wave wv takes {wv, wv+4, ...}
#pragma unroll
    for (int jj = 0; jj < 6; ++jj) {
      const int c = wv + 4 * jj;
      const int p = c >> 3, r16 = (c & 7) * 16;
      gld_lds16(base[p] + (size_t)(r16 + rl) * K + kt + cl, &lds[p][r16][0]);
    }
    __syncthreads();
    frag_t af[2][4];
#pragma unroll
    for (int mf = 0; mf < 4; ++mf) {
      af[0][mf] = *(const frag_t*)&lds[0][wm + mf * 16 + lm][g * 8];
      af[1][mf] = *(const frag_t*)&lds[1][wm + mf * 16 + lm][g * 8];
    }
#pragma unroll
    for (int nf = 0; nf < 4; ++nf) {
      frag_t bhf = *(const frag_t*)&lds[2][wn + nf * 16 + lm][g * 8];
#pragma unroll
      for (int mf = 0; mf < 4; ++mf) {
        acc[mf][nf] = mfma16(af[0][mf], bhf, acc[mf][nf]);
        acc[mf][nf] = mfma16(af[1][mf], bhf, acc[mf][nf]);
      }
    }
    __syncthreads();
  }
  const float* bias = args.bias[z];
  uint16_t* oH = args.oH[z];
  uint16_t* oL = args.oL[z];
#pragma unroll
  for (int mf = 0; mf < 4; ++mf) {
#pragma unroll
    for (int nf = 0; nf < 4; ++nf) {
      const int col = gn0 + wn + nf * 16 + lm;
#pragma unroll
      for (int i = 0; i < 4; ++i) {
        const int row = gm0 + wm + mf * 16 + g * 4 + i;
        float v = acc[mf][nf][i] + (isT ? bias[row] : bias[col]);
        uint16_t h, l;
        split2(v, h, l);
        size_t addr;
        if (!isT) {
          addr = ((size_t)((row >> 11) * 16 + (col >> 6)) * 2048 + (row & 2047)) * 64 +
                 (col & 63);
          oH[addr] = h;
          oL[addr] = l;
        } else {
          addr = ((size_t)((col >> 11) * 1024 + row)) * 2048 + (col & 2047);
          oH[addr] = h;  // V^T hi only (PV is 1-term)
        }
      }
    }
  }
}

// ---------- O projection x2: C = (Oh+Ol) * Woh^T + bo, fp32 out ----------
__global__ __launch_bounds__(256, 2) void gemm_o(
    const uint16_t* __restrict__ Ah, const uint16_t* __restrict__ Al,
    const uint16_t* __restrict__ Bh, const float* __restrict__ bias,
    float* __restrict__ out) {
  const int K = 1024, N = 1024;
  __shared__ uint16_t ldsA[2][64][32];   // 8 KB
  __shared__ uint16_t ldsB[128][32];     // 8 KB
  const int tid = threadIdx.x;
  const int wv = tid >> 6, lane = tid & 63;
  const int lm = lane & 15, g = lane >> 4;
  const int wm = (wv & 1) * 32, wn = (wv >> 1) * 64;
  const int t = blockIdx.x + 8 * blockIdx.y;
  const int kx = t & 7, j = t >> 3;
  const int sx = (j & 3) | ((kx & 1) << 2);
  const int sy = (j >> 2) | ((kx >> 1) << 4);
  const int gm0 = sy * 64, gn0 = sx * 128;
  const uint16_t* baseA[2] = {Ah + (size_t)gm0 * K, Al + (size_t)gm0 * K};
  const uint16_t* baseB = Bh + (size_t)gn0 * K;
  const int rl = lane >> 2, cl = (lane & 3) * 8;

  f32x4 acc[2][4];
#pragma unroll
  for (int a = 0; a < 2; ++a)
#pragma unroll
    for (int b = 0; b < 4; ++b) acc[a][b] = (f32x4)0.0f;

#pragma unroll 1
  for (int kt = 0; kt < K; kt += 32) {
#pragma unroll
    for (int jj = 0; jj < 4; ++jj) {
      const int c = wv + 4 * jj;  // 16 chunks: 8 A + 8 B
      if (c < 8) {
        const int p = c >> 2, r16 = (c & 3) * 16;
        gld_lds16(baseA[p] + (size_t)(r16 + rl) * K + kt + cl, &ldsA[p][r16][0]);
      } else {
        const int b = c - 8;
        gld_lds16(baseB + (size_t)(b * 16 + rl) * K + kt + cl, &ldsB[b * 16][0]);
      }
    }
    __syncthreads();
    frag_t af[2][2];
#pragma unroll
    for (int mf = 0; mf < 2; ++mf) {
      af[0][mf] = *(const frag_t*)&ldsA[0][wm + mf * 16 + lm][g * 8];
      af[1][mf] = *(const frag_t*)&ldsA[1][wm + mf * 16 + lm][g * 8];
    }
#pragma unroll
    for (int nf = 0; nf < 4; ++nf) {
      frag_t bhf = *(const frag_t*)&ldsB[wn + nf * 16 + lm][g * 8];
#pragma unroll
      for (int mf = 0; mf < 2; ++mf) {
        acc[mf][nf] = mfma16(af[0][mf], bhf, acc[mf][nf]);
        acc[mf][nf] = mfma16(af[1][mf], bhf, acc[mf][nf]);
      }
    }
    __syncthreads();
  }
#pragma unroll
  for (int mf = 0; mf < 2; ++mf)
#pragma unroll
    for (int nf = 0; nf < 4; ++nf) {
      const int col = gn0 + wn + nf * 16 + lm;
#pragma unroll
      for (int i = 0; i < 4; ++i) {
        const int row = gm0 + wm + mf * 16 + g * 4 + i;
        out[(size_t)row * N + col] = acc[mf][nf][i] + bias[col];
      }
    }
}

// ---------- fused attention v7: PV 1-term (V-hi only), 40 KB LDS ----------
// S^T keeps 3 terms (score accuracy); PV drops V-lo (damped by softmax avg).
// LDS 40 KB -> 4 blocks/CU (VGPR ~100 natural, no launch_bounds cap beyond 2
// -- r5/r6 lesson: caps only spill; residency follows actual resources).
__global__ __launch_bounds__(256, 2) void attn_kernel(
    const uint16_t* __restrict__ Qh, const uint16_t* __restrict__ Ql,
    const uint16_t* __restrict__ Kh, const uint16_t* __restrict__ Kl,
    const uint16_t* __restrict__ Vh,
    float* __restrict__ opart, float* __restrict__ lpart) {
  __shared__ uint16_t kt[2][4096];  // K tile [kv 64][hd 64] hi/lo, swizzled
  __shared__ uint16_t vt[4096];     // V^T tile [d 64][kv 64] hi, swizzled
  __shared__ uint16_t pp[8192];     // P (bf16 hi) [qrow 128][kv 64], swizzled
  const int tid = threadIdx.x;
  const int wave = tid >> 6, lane = tid & 63;
  const int lm = lane & 15, g = lane >> 4;
  const int linear = blockIdx.x + 32 * blockIdx.y;
  const int bh = (linear & 7) + 8 * (linear >> 8);
  const int qt = (linear >> 3) & 15;
  const int half = (linear >> 7) & 1;
  const int kvh = half * 1024;
  const size_t base = (size_t)bh * 131072;
  const int q0 = qt * 128 + wave * 32;

  frag_t qf[2][2][2];  // [plane][b(q-16-tile)][ks]
#pragma unroll
  for (int b = 0; b < 2; ++b) {
    const size_t rb = base + (size_t)(q0 + b * 16 + lm) * 64 + g * 8;
#pragma unroll
    for (int ks = 0; ks < 2; ++ks) {
      qf[0][b][ks] = *(const frag_t*)(Qh + rb + ks * 32);
      qf[1][b][ks] = *(const frag_t*)(Ql + rb + ks * 32);
    }
  }
  f32x4 oacc[2][4];
  f32x4 lacc[2];
#pragma unroll
  for (int mf = 0; mf < 2; ++mf) {
    lacc[mf] = (f32x4)0.0f;
#pragma unroll
    for (int nf = 0; nf < 4; ++nf) oacc[mf][nf] = (f32x4)0.0f;
  }
  short8 ones_s = (short8)(short)0x3F80;
  frag_t ones = __builtin_bit_cast(frag_t, ones_s);

  const int sr = tid >> 3;       // 0..31
  const int sc = (tid & 7) * 8;  // 0..56

  // named prefetch registers (r7 lesson: no arrays, no lambda capture)
  uint4 kr0, kr1, kr2, kr3, vr0, vr1;
  {
    const size_t ka = base + (size_t)(kvh + sr) * 64 + sc;
    kr0 = *(const uint4*)(Kh + ka);
    kr1 = *(const uint4*)(Kh + ka + 2048);
    kr2 = *(const uint4*)(Kl + ka);
    kr3 = *(const uint4*)(Kl + ka + 2048);
  }

  const float kExpScale = 0.12500000f * 1.44269504f;  // /8, exp->exp2

#pragma unroll 1
  for (int it = 0; it < 16; ++it) {
    const int kv0 = kvh + it * 64;
    *(uint4*)&kt[0][swz(sr, sc)] = kr0;
    *(uint4*)&kt[0][swz(sr + 32, sc)] = kr1;
    *(uint4*)&kt[1][swz(sr, sc)] = kr2;
    *(uint4*)&kt[1][swz(sr + 32, sc)] = kr3;
    __syncthreads();  // barrier 1: K published; prev-iter vt reads done
    {                 // issue V loads; hidden by S^T MFMAs
      const size_t va = base + (size_t)sr * 2048 + kv0 + sc;
      vr0 = *(const uint4*)(Vh + va);
      vr1 = *(const uint4*)(Vh + va + 65536);
    }
    f32x4 sct[4][2];
#pragma unroll
    for (int a = 0; a < 4; ++a)
#pragma unroll
      for (int b = 0; b < 2; ++b) sct[a][b] = (f32x4)0.0f;
#pragma unroll
    for (int ks = 0; ks < 2; ++ks) {
#pragma unroll
      for (int a = 0; a < 4; ++a) {
        frag_t kfh = *(const frag_t*)&kt[0][swz(a * 16 + lm, ks * 32 + g * 8)];
        frag_t kfl = *(const frag_t*)&kt[1][swz(a * 16 + lm, ks * 32 + g * 8)];
#pragma unroll
        for (int b = 0; b < 2; ++b) {
          sct[a][b] = mfma16(kfh, qf[0][b][ks], sct[a][b]);
          sct[a][b] = mfma16(kfl, qf[0][b][ks], sct[a][b]);
          sct[a][b] = mfma16(kfh, qf[1][b][ks], sct[a][b]);
        }
      }
    }
#pragma unroll
    for (int a = 0; a < 4; ++a) {
#pragma unroll
      for (int b = 0; b < 2; ++b) {
        ushort4 pk;
        pk.x = bf16_rne(exp2f(kExpScale * sct[a][b][0]));
        pk.y = bf16_rne(exp2f(kExpScale * sct[a][b][1]));
        pk.z = bf16_rne(exp2f(kExpScale * sct[a][b][2]));
        pk.w = bf16_rne(exp2f(kExpScale * sct[a][b][3]));
        *(ushort4*)&pp[swz(wave * 32 + b * 16 + lm, a * 16 + g * 4)] = pk;
      }
    }
    *(uint4*)&vt[swz(sr, sc)] = vr0;
    *(uint4*)&vt[swz(sr + 32, sc)] = vr1;
    __syncthreads();  // barrier 2: V published; all waves' K reads done
    if (it + 1 < 16) {  // next K loads; hidden by PV MFMAs
      const size_t ka = base + (size_t)(kv0 + 64 + sr) * 64 + sc;
      kr0 = *(const uint4*)(Kh + ka);
      kr1 = *(const uint4*)(Kh + ka + 2048);
      kr2 = *(const uint4*)(Kl + ka);
      kr3 = *(const uint4*)(Kl + ka + 2048);
    }
#pragma unroll
    for (int ks = 0; ks < 2; ++ks) {
      frag_t pa[2];
#pragma unroll
      for (int mf = 0; mf < 2; ++mf) {
        pa[mf] = *(const frag_t*)&pp[swz(wave * 32 + mf * 16 + lm, ks * 32 + g * 8)];
        lacc[mf] = mfma16(pa[mf], ones, lacc[mf]);
      }
#pragma unroll
      for (int nf = 0; nf < 4; ++nf) {
        frag_t vbh = *(const frag_t*)&vt[swz(nf * 16 + lm, ks * 32 + g * 8)];
#pragma unroll
        for (int mf = 0; mf < 2; ++mf) {
          oacc[mf][nf] = mfma16(pa[mf], vbh, oacc[mf][nf]);
        }
      }
    }
  }
  const int obase = (half * 32 + bh) * 2048;
#pragma unroll
  for (int mf = 0; mf < 2; ++mf) {
#pragma unroll
    for (int i = 0; i < 4; ++i) {
      const int qrow = qt * 128 + wave * 32 + mf * 16 + g * 4 + i;
      float* orow = opart + ((size_t)obase + qrow) * 64;
#pragma unroll
      for (int nf = 0; nf < 4; ++nf) orow[nf * 16 + lm] = oacc[mf][nf][i];
      if (lm == 0) lpart[obase + qrow] = lacc[mf][i];
    }
  }
}

// ---------- combine partials, normalize, split to bf16 planes ----------
__global__ void combine_kernel(const float* __restrict__ opart,
                               const float* __restrict__ lpart,
                               uint16_t* __restrict__ oh, uint16_t* __restrict__ ol) {
  const int idx = blockIdx.x * 256 + threadIdx.x;
  const float4 a = ((const float4*)opart)[idx];
  const float4 b = ((const float4*)(opart + 4194304))[idx];
  const int row = idx >> 4;
  const float linv = 1.0f / (lpart[row] + lpart[65536 + row]);
  const int bh = row >> 11, qq = row & 2047;
  const int bb = bh >> 4, hh = bh & 15;
  const size_t o = ((size_t)(bb * 2048 + qq)) * 1024 + hh * 64 + (idx & 15) * 4;
  ushort4 H, L;
  float v;
  v = (a.x + b.x) * linv; split2(v, H.x, L.x);
  v = (a.y + b.y) * linv; split2(v, H.y, L.y);
  v = (a.z + b.z) * linv; split2(v, H.z, L.z);
  v = (a.w + b.w) * linv; split2(v, H.w, L.w);
  *(ushort4*)(oh + o) = H;
  *(ushort4*)(ol + o) = L;
}

extern "C" void kernel_launch(void* const* d_in, const int* in_sizes, int n_in,
                              void* d_out, int out_size, void* d_ws, size_t ws_size,
                              hipStream_t stream) {
  const float* q = (const float*)d_in[0];
  const float* k = (const float*)d_in[1];
  const float* v = (const float*)d_in[2];
  const float* Wq = (const float*)d_in[3];
  const float* bq = (const float*)d_in[4];
  const float* Wk = (const float*)d_in[5];
  const float* bk = (const float*)d_in[6];
  const float* Wv = (const float*)d_in[7];
  const float* bv = (const float*)d_in[8];
  const float* Wo = (const float*)d_in[9];
  const float* bo = (const float*)d_in[10];

  const size_t NX = 4194304;  // B*S*H
  const size_t NW = 1048576;  // H*H
  uint16_t* p = (uint16_t*)d_ws;
  uint16_t* xqh = p; p += NX; uint16_t* xql = p; p += NX;
  uint16_t* xkh = p; p += NX; uint16_t* xkl = p; p += NX;
  uint16_t* xvh = p; p += NX; uint16_t* xvl = p; p += NX;  // xvl unused (kept for layout)
  uint16_t* wqh = p; p += NW; uint16_t* wql = p; p += NW;  // wql unused
  uint16_t* wkh = p; p += NW; uint16_t* wkl = p; p += NW;  // wkl unused
  uint16_t* wvh = p; p += NW; uint16_t* wvl = p; p += NW;
  uint16_t* woh = p; p += NW; uint16_t* wol = p; p += NW;  // wol unused
  uint16_t* qph = p; p += NX; uint16_t* qpl = p; p += NX;
  uint16_t* kph = p; p += NX; uint16_t* kpl = p; p += NX;
  uint16_t* vth = p; p += NX; uint16_t* vtl = p; p += NX;  // vtl unused
  uint16_t* oh = xqh;  // alias: xq consumed before combine writes o
  uint16_t* ol = xql;
  float* opart = (float*)xkh;          // 33.6 MB over xkh..xvl (dead after qkv)
  float* lpart = opart + 2 * 4194304;  // 0.5 MB into wq region (dead after qkv)

  SplitArgs sx;
  sx.src[0] = q;  sx.hi[0] = xqh; sx.lo[0] = xql;
  sx.src[1] = k;  sx.hi[1] = xkh; sx.lo[1] = xkl;
  sx.src[2] = v;  sx.hi[2] = xvh; sx.lo[2] = nullptr;  // v hi-only
  sx.src[3] = nullptr; sx.hi[3] = nullptr; sx.lo[3] = nullptr;
  sx.n4 = (int)(NX / 4);
  split_multi<<<dim3((unsigned)(NX / 4 / 256), 3), 256, 0, stream>>>(sx);

  SplitArgs sw;
  sw.src[0] = Wq; sw.hi[0] = wqh; sw.lo[0] = nullptr;
  sw.src[1] = Wk; sw.hi[1] = wkh; sw.lo[1] = nullptr;
  sw.src[2] = Wv; sw.hi[2] = wvh; sw.lo[2] = wvl;  // Wv needs lo (A-side of z=2)
  sw.src[3] = Wo; sw.hi[3] = woh; sw.lo[3] = nullptr;
  sw.n4 = (int)(NW / 4);
  split_multi<<<dim3((unsigned)(NW / 4 / 256), 4), 256, 0, stream>>>(sw);

  QKVArgs qa;
  qa.Ah[0] = xqh; qa.Al[0] = xql; qa.Bh[0] = wqh;
  qa.bias[0] = bq; qa.oH[0] = qph; qa.oL[0] = qpl;
  qa.Ah[1] = xkh; qa.Al[1] = xkl; qa.Bh[1] = wkh;
  qa.bias[1] = bk; qa.oH[1] = kph; qa.oL[1] = kpl;
  qa.Ah[2] = wvh; qa.Al[2] = wvl; qa.Bh[2] = xvh;  // swapped -> V^T, hi-only out
  qa.bias[2] = bv; qa.oH[2] = vth; qa.oL[2] = vtl;
  gemm_qkv<<<dim3(8, 32, 3), 256, 0, stream>>>(qa);

  attn_kernel<<<dim3(32, 32), 256, 0, stream>>>(qph, qpl, kph, kpl, vth,
                                                opart, lpart);
  combine_kernel<<<4096, 256, 0, stream>>>(opart, lpart, oh, ol);

  gemm_o<<<dim3(8, 64), 256, 0, stream>>>(oh, ol, woh, bo, (float*)d_out);
}